// Round 2
// baseline (329.561 us; speedup 1.0000x reference)
//
#include <hip/hip_runtime.h>
#include <stdint.h>

#define NSEQ 1032
#define CDIM 1024
#define HD 64
#define H_HEADS 16
#define BROWS 4128
#define SCALE 0.125f

typedef __attribute__((ext_vector_type(8))) short bf16x8;
typedef __attribute__((ext_vector_type(4))) float f32x4;

__device__ __forceinline__ unsigned short f2bf(float f) {
  union { float f; uint32_t u; } c; c.f = f;
  uint32_t u = c.u;
  return (unsigned short)((u + 0x7fffu + ((u >> 16) & 1u)) >> 16);
}

__device__ __forceinline__ void gl16(const void* gp, void* lp) {
  __builtin_amdgcn_global_load_lds((const __attribute__((address_space(1))) void*)gp,
                                   (__attribute__((address_space(3))) void*)lp, 16, 0, 0);
}

__global__ void convert_f32_bf16(const float* __restrict__ src, unsigned short* __restrict__ dst, int n4) {
  int i = blockIdx.x * blockDim.x + threadIdx.x;
  if (i >= n4) return;
  float4 v = ((const float4*)src)[i];
  ushort4 o;
  o.x = f2bf(v.x); o.y = f2bf(v.y); o.z = f2bf(v.z); o.w = f2bf(v.w);
  ((ushort4*)dst)[i] = o;
}

// C[m][j] = sum_k A[m][k] * Bw[j][k] + bias[j]
// MODE 0: scatter to K [64][1032][64] and V^T [64][64][1032] (bf16)
// MODE 1: write fp32 out [M][1024]
template<int MODE>
__global__ __launch_bounds__(256, 2) void gemm_bt(
    const unsigned short* __restrict__ A,
    const unsigned short* __restrict__ Bw,
    const float* __restrict__ bias,
    unsigned short* __restrict__ outK,
    unsigned short* __restrict__ outV,
    float* __restrict__ outF,
    int M, int K)
{
  __shared__ unsigned short As[128 * 32];
  __shared__ unsigned short Bs[128 * 32];
  const int t = threadIdx.x;
  const int w = t >> 6, lane = t & 63, lr = lane & 15, lg = lane >> 4;
  const int wr = w >> 1, wc = w & 1;
  const int m0 = blockIdx.y * 128, n0 = blockIdx.x * 128;
  f32x4 acc[4][4] = {};

  for (int ks = 0; ks < K; ks += 32) {
    #pragma unroll
    for (int q = 0; q < 2; ++q) {
      const int o = t + (q << 8);          // 16B chunk id 0..511
      const int row = o >> 2, kc = o & 3;  // 128 rows x 4 chunks
      int ra = m0 + row; ra = ra < M ? ra : M - 1;
      gl16(A + (size_t)ra * K + ks + kc * 8, (void*)(As + o * 8));
      gl16(Bw + (size_t)(n0 + row) * K + ks + kc * 8, (void*)(Bs + o * 8));
    }
    __syncthreads();
    bf16x8 af[4], bfr[4];
    #pragma unroll
    for (int m = 0; m < 4; ++m)
      af[m] = *(const bf16x8*)(As + (wr * 64 + m * 16 + lr) * 32 + lg * 8);
    #pragma unroll
    for (int n = 0; n < 4; ++n)
      bfr[n] = *(const bf16x8*)(Bs + (wc * 64 + n * 16 + lr) * 32 + lg * 8);
    #pragma unroll
    for (int m = 0; m < 4; ++m)
      #pragma unroll
      for (int n = 0; n < 4; ++n)
        acc[m][n] = __builtin_amdgcn_mfma_f32_16x16x32_bf16(af[m], bfr[n], acc[m][n], 0, 0, 0);
    __syncthreads();
  }

  #pragma unroll
  for (int m = 0; m < 4; ++m) {
    const int rowb = m0 + wr * 64 + m * 16 + lg * 4;
    #pragma unroll
    for (int n = 0; n < 4; ++n) {
      const int col = n0 + wc * 64 + n * 16 + lr;
      const float bv = bias[col];
      #pragma unroll
      for (int r = 0; r < 4; ++r) {
        const int row = rowb + r;
        if (row >= M) continue;
        const float v = acc[m][n][r] + bv;
        if (MODE == 0) {
          const int b = row / NSEQ, nn = row - b * NSEQ;
          if (col < CDIM) {
            const int h = col >> 6, d = col & 63;
            outK[((size_t)(b * H_HEADS + h) * NSEQ + nn) * HD + d] = f2bf(v);
          } else {
            const int jj = col - CDIM, h = jj >> 6, d = jj & 63;
            outV[((size_t)(b * H_HEADS + h) * HD + d) * NSEQ + nn] = f2bf(v);
          }
        } else {
          outF[(size_t)row * CDIM + col] = v;
        }
      }
    }
  }
}

// One block: (head bh, row-tile rt). 4 waves x 16 rows. Streams 17 col-tiles of 64.
__global__ __launch_bounds__(256, 4) void attn_kernel(
    const unsigned short* __restrict__ Kb,   // [64][1032][64] bf16
    const unsigned short* __restrict__ Vt,   // [64][64][1032] bf16
    const float* __restrict__ addm,          // [1032][1032]
    const float* __restrict__ rcs,           // [64][1032][1032]
    unsigned short* __restrict__ outp)       // [4128][1024] bf16
{
  __shared__ unsigned short Kc[64 * 72];  // [m][d], padded stride 72
  __shared__ unsigned short Vs[64 * 72];  // [d][m], padded stride 72
  __shared__ unsigned short Ps[64 * 72];  // [i][m], padded stride 72
  __shared__ unsigned short Rs[64 * 72];  // [i][m] rcs bf16, padded stride 72
  const int t = threadIdx.x;
  const int w = t >> 6, lane = t & 63, lr = lane & 15, lg = lane >> 4;
  const int bh = blockIdx.y;
  const int rt = blockIdx.x;
  const int i_base = rt * 64 + w * 16;

  // hoist Kr A-fragments (rows i_base..i_base+15, d 0..63)
  bf16x8 akr[2];
  {
    int row = i_base + lr; if (row > NSEQ - 1) row = NSEQ - 1;
    const unsigned short* p = Kb + ((size_t)bh * NSEQ + row) * HD + lg * 8;
    akr[0] = *(const bf16x8*)(p);
    akr[1] = *(const bf16x8*)(p + 32);
  }

  // rcs staging geometry (wave-private stripe of 16 rows x 64 cols)
  const int rrow = lane >> 2;            // 0..15
  const int colbase = (lane & 3) * 16;   // 0,16,32,48
  int rgi = i_base + rrow; if (rgi > NSEQ - 1) rgi = NSEQ - 1;
  const float* rrow_ptr = rcs + ((size_t)bh * NSEQ + rgi) * NSEQ;

  f32x4 accP[4] = {};
  f32x4 accR[4] = {};
  float lsum[4] = {0.f, 0.f, 0.f, 0.f};

  for (int mt = 0; mt < 17; ++mt) {
    const int mB = mt * 64;
    // stage Kc[m][d] and Vs[d][m]
    #pragma unroll
    for (int q = 0; q < 2; ++q) {
      const int o = t + (q << 8);          // 0..511, 64 rows x 8 chunks
      const int row = o >> 3, ch = o & 7;
      int mrow = mB + row; if (mrow > NSEQ - 1) mrow = NSEQ - 1;
      bf16x8 kv = *(const bf16x8*)(Kb + ((size_t)bh * NSEQ + mrow) * HD + ch * 8);
      *(bf16x8*)(Kc + row * 72 + ch * 8) = kv;
      int cb = mB + ch * 8; if (cb + 8 > NSEQ) cb = NSEQ - 8;
      bf16x8 vv = *(const bf16x8*)(Vt + ((size_t)bh * HD + row) * NSEQ + cb);
      *(bf16x8*)(Vs + row * 72 + ch * 8) = vv;
    }

    // issue this tile's rcs loads early (coalesced 64B-chunk float4 loads);
    // conversion/LDS-write happens after the S MFMAs so HBM latency hides.
    float tf[16];
    if (mB + colbase + 16 <= NSEQ) {
      #pragma unroll
      for (int q4 = 0; q4 < 4; ++q4) {
        float4 v = *(const float4*)(rrow_ptr + mB + colbase + q4 * 4);
        tf[q4 * 4 + 0] = v.x; tf[q4 * 4 + 1] = v.y;
        tf[q4 * 4 + 2] = v.z; tf[q4 * 4 + 3] = v.w;
      }
    } else {
      #pragma unroll
      for (int j = 0; j < 16; ++j) {
        const int gc = mB + colbase + j;
        tf[j] = (gc < NSEQ) ? rrow_ptr[gc] : 0.f;
      }
    }

    __syncthreads();

    // S = Kr @ Kc^T  (16 x 64 per wave)
    f32x4 s[4];
    #pragma unroll
    for (int fn = 0; fn < 4; ++fn) {
      f32x4 z = {0.f, 0.f, 0.f, 0.f};
      bf16x8 b0 = *(const bf16x8*)(Kc + (16 * fn + lr) * 72 + lg * 8);
      bf16x8 b1 = *(const bf16x8*)(Kc + (16 * fn + lr) * 72 + 32 + lg * 8);
      z = __builtin_amdgcn_mfma_f32_16x16x32_bf16(akr[0], b0, z, 0, 0, 0);
      z = __builtin_amdgcn_mfma_f32_16x16x32_bf16(akr[1], b1, z, 0, 0, 0);
      s[fn] = z;
    }

    // p = exp(scale*s + add); accumulate row sums; stash bf16 P in LDS
    const int irow_base = i_base + lg * 4;
    #pragma unroll
    for (int fn = 0; fn < 4; ++fn) {
      const int mcol = mB + 16 * fn + lr;
      const int mc = mcol > NSEQ - 1 ? NSEQ - 1 : mcol;
      #pragma unroll
      for (int r = 0; r < 4; ++r) {
        int irow = irow_base + r; int ic = irow > NSEQ - 1 ? NSEQ - 1 : irow;
        float sv = s[fn][r] * SCALE + addm[(size_t)ic * NSEQ + mc];
        float p = (mcol < NSEQ) ? __expf(sv) : 0.f;
        lsum[r] += p;
        Ps[(w * 16 + lg * 4 + r) * 72 + 16 * fn + lr] = f2bf(p);
      }
    }

    // convert staged rcs to bf16, write wave-private LDS stripe, read fragments
    {
      bf16x8 a0, a1;
      #pragma unroll
      for (int j = 0; j < 8; ++j) { a0[j] = (short)f2bf(tf[j]); a1[j] = (short)f2bf(tf[j + 8]); }
      *(bf16x8*)(Rs + (w * 16 + rrow) * 72 + colbase) = a0;
      *(bf16x8*)(Rs + (w * 16 + rrow) * 72 + colbase + 8) = a1;
    }
    bf16x8 pr0 = *(const bf16x8*)(Rs + (w * 16 + lr) * 72 + lg * 8);
    bf16x8 pr1 = *(const bf16x8*)(Rs + (w * 16 + lr) * 72 + 32 + lg * 8);

    // PV: accP += P @ V, accR += RCS @ V
    bf16x8 pa0 = *(const bf16x8*)(Ps + (w * 16 + lr) * 72 + lg * 8);
    bf16x8 pa1 = *(const bf16x8*)(Ps + (w * 16 + lr) * 72 + 32 + lg * 8);
    #pragma unroll
    for (int fd = 0; fd < 4; ++fd) {
      bf16x8 v0 = *(const bf16x8*)(Vs + (16 * fd + lr) * 72 + lg * 8);
      bf16x8 v1 = *(const bf16x8*)(Vs + (16 * fd + lr) * 72 + 32 + lg * 8);
      accP[fd] = __builtin_amdgcn_mfma_f32_16x16x32_bf16(pa0, v0, accP[fd], 0, 0, 0);
      accP[fd] = __builtin_amdgcn_mfma_f32_16x16x32_bf16(pa1, v1, accP[fd], 0, 0, 0);
      accR[fd] = __builtin_amdgcn_mfma_f32_16x16x32_bf16(pr0, v0, accR[fd], 0, 0, 0);
      accR[fd] = __builtin_amdgcn_mfma_f32_16x16x32_bf16(pr1, v1, accR[fd], 0, 0, 0);
    }
    __syncthreads();
  }

  // reduce lsum across the 16 lanes of this row-group (cols 0..15 per lane)
  #pragma unroll
  for (int r = 0; r < 4; ++r) {
    float v = lsum[r];
    v += __shfl_xor(v, 1); v += __shfl_xor(v, 2);
    v += __shfl_xor(v, 4); v += __shfl_xor(v, 8);
    lsum[r] = v;
  }

  const int b = bh >> 4, hh = bh & 15;
  #pragma unroll
  for (int fd = 0; fd < 4; ++fd) {
    #pragma unroll
    for (int r = 0; r < 4; ++r) {
      const int irow = i_base + lg * 4 + r;
      if (irow < NSEQ) {
        const float val = 0.8f * accP[fd][r] / lsum[r] + 1.2f * accR[fd][r];
        outp[(size_t)(b * NSEQ + irow) * CDIM + hh * 64 + 16 * fd + lr] = f2bf(val);
      }
    }
  }
}

extern "C" void kernel_launch(void* const* d_in, const int* in_sizes, int n_in,
                              void* d_out, int out_size, void* d_ws, size_t ws_size,
                              hipStream_t stream) {
  (void)in_sizes; (void)n_in; (void)out_size; (void)ws_size;
  const float* x      = (const float*)d_in[0];
  const float* qkv_w  = (const float*)d_in[1];
  const float* qkv_b  = (const float*)d_in[2];
  const float* proj_w = (const float*)d_in[3];
  const float* proj_b = (const float*)d_in[4];
  const float* addm   = (const float*)d_in[5];
  const float* rcs    = (const float*)d_in[6];
  float* out = (float*)d_out;

  char* ws = (char*)d_ws;
  unsigned short* x_bf = (unsigned short*)ws; ws += (size_t)BROWS * CDIM * 2;
  unsigned short* wkv  = (unsigned short*)ws; ws += (size_t)2048 * CDIM * 2;
  unsigned short* wp   = (unsigned short*)ws; ws += (size_t)1024 * CDIM * 2;
  unsigned short* Kb   = (unsigned short*)ws; ws += (size_t)64 * NSEQ * HD * 2;
  unsigned short* Vt   = (unsigned short*)ws; ws += (size_t)64 * HD * NSEQ * 2;
  unsigned short* op   = (unsigned short*)ws; ws += (size_t)BROWS * CDIM * 2;

  const int n1 = BROWS * CDIM / 4, n2 = 2048 * CDIM / 4, n3 = 1024 * CDIM / 4;
  convert_f32_bf16<<<(n1 + 255) / 256, 256, 0, stream>>>(x, x_bf, n1);
  convert_f32_bf16<<<(n2 + 255) / 256, 256, 0, stream>>>(qkv_w + 1024 * 1024, wkv, n2);
  convert_f32_bf16<<<(n3 + 255) / 256, 256, 0, stream>>>(proj_w, wp, n3);

  // K/V projection (q is unused by the reference math — skipped)
  gemm_bt<0><<<dim3(16, 33), 256, 0, stream>>>(x_bf, wkv, qkv_b + 1024, Kb, Vt, nullptr, BROWS, CDIM);
  attn_kernel<<<dim3(17, 64), 256, 0, stream>>>(Kb, Vt, addm, rcs, op);
  gemm_bt<1><<<dim3(8, 33), 256, 0, stream>>>(op, wp, proj_b, nullptr, nullptr, out, BROWS, CDIM);
}

// Round 3
// 266.597 us; speedup vs baseline: 1.2362x; 1.2362x over previous
//
#include <hip/hip_runtime.h>
#include <stdint.h>

#define NSEQ 1032
#define CDIM 1024
#define HD 64
#define H_HEADS 16
#define BROWS 4128
#define SCALE 0.125f

typedef __attribute__((ext_vector_type(8))) short bf16x8;
typedef __attribute__((ext_vector_type(4))) float f32x4;

__device__ __forceinline__ unsigned short f2bf(float f) {
  union { float f; uint32_t u; } c; c.f = f;
  uint32_t u = c.u;
  return (unsigned short)((u + 0x7fffu + ((u >> 16) & 1u)) >> 16);
}

__device__ __forceinline__ float bf2f(unsigned short b) {
  union { uint32_t u; float f; } c; c.u = ((uint32_t)b) << 16;
  return c.f;
}

__device__ __forceinline__ void gl16(const void* gp, void* lp) {
  __builtin_amdgcn_global_load_lds((const __attribute__((address_space(1))) void*)gp,
                                   (__attribute__((address_space(3))) void*)lp, 16, 0, 0);
}

__global__ void convert_f32_bf16(const float* __restrict__ src, unsigned short* __restrict__ dst, int n4) {
  int i = blockIdx.x * blockDim.x + threadIdx.x;
  if (i >= n4) return;
  float4 v = ((const float4*)src)[i];
  ushort4 o;
  o.x = f2bf(v.x); o.y = f2bf(v.y); o.z = f2bf(v.z); o.w = f2bf(v.w);
  ((ushort4*)dst)[i] = o;
}

// C[m][j] = sum_k A[m][k] * Bw[j][k] + bias[j]
// MODE 0: scatter to K [64][1032][64] and V^T [64][64][1032] (bf16)
// MODE 1: write fp32 out [M][1024]
template<int MODE>
__global__ __launch_bounds__(256, 2) void gemm_bt(
    const unsigned short* __restrict__ A,
    const unsigned short* __restrict__ Bw,
    const float* __restrict__ bias,
    unsigned short* __restrict__ outK,
    unsigned short* __restrict__ outV,
    float* __restrict__ outF,
    int M, int K)
{
  __shared__ unsigned short As[128 * 32];
  __shared__ unsigned short Bs[128 * 32];
  const int t = threadIdx.x;
  const int w = t >> 6, lane = t & 63, lr = lane & 15, lg = lane >> 4;
  const int wr = w >> 1, wc = w & 1;
  const int m0 = blockIdx.y * 128, n0 = blockIdx.x * 128;
  f32x4 acc[4][4] = {};

  for (int ks = 0; ks < K; ks += 32) {
    #pragma unroll
    for (int q = 0; q < 2; ++q) {
      const int o = t + (q << 8);          // 16B chunk id 0..511
      const int row = o >> 2, kc = o & 3;  // 128 rows x 4 chunks
      int ra = m0 + row; ra = ra < M ? ra : M - 1;
      gl16(A + (size_t)ra * K + ks + kc * 8, (void*)(As + o * 8));
      gl16(Bw + (size_t)(n0 + row) * K + ks + kc * 8, (void*)(Bs + o * 8));
    }
    __syncthreads();
    bf16x8 af[4], bfr[4];
    #pragma unroll
    for (int m = 0; m < 4; ++m)
      af[m] = *(const bf16x8*)(As + (wr * 64 + m * 16 + lr) * 32 + lg * 8);
    #pragma unroll
    for (int n = 0; n < 4; ++n)
      bfr[n] = *(const bf16x8*)(Bs + (wc * 64 + n * 16 + lr) * 32 + lg * 8);
    #pragma unroll
    for (int m = 0; m < 4; ++m)
      #pragma unroll
      for (int n = 0; n < 4; ++n)
        acc[m][n] = __builtin_amdgcn_mfma_f32_16x16x32_bf16(af[m], bfr[n], acc[m][n], 0, 0, 0);
    __syncthreads();
  }

  #pragma unroll
  for (int m = 0; m < 4; ++m) {
    const int rowb = m0 + wr * 64 + m * 16 + lg * 4;
    #pragma unroll
    for (int n = 0; n < 4; ++n) {
      const int col = n0 + wc * 64 + n * 16 + lr;
      const float bv = bias[col];
      #pragma unroll
      for (int r = 0; r < 4; ++r) {
        const int row = rowb + r;
        if (row >= M) continue;
        const float v = acc[m][n][r] + bv;
        if (MODE == 0) {
          const int b = row / NSEQ, nn = row - b * NSEQ;
          if (col < CDIM) {
            const int h = col >> 6, d = col & 63;
            outK[((size_t)(b * H_HEADS + h) * NSEQ + nn) * HD + d] = f2bf(v);
          } else {
            const int jj = col - CDIM, h = jj >> 6, d = jj & 63;
            outV[((size_t)(b * H_HEADS + h) * HD + d) * NSEQ + nn] = f2bf(v);
          }
        } else {
          outF[(size_t)row * CDIM + col] = v;
        }
      }
    }
  }
}

// Softmax part only: op[b][i][h*64+d] = 0.8 * (P@V)/l   (bf16)
// grid: 1088 blocks (17 row-tiles x 64 heads), XCD-swizzled
__global__ __launch_bounds__(256, 4) void attn_sm(
    const unsigned short* __restrict__ Kb,   // [64][1032][64] bf16
    const unsigned short* __restrict__ Vt,   // [64][64][1032] bf16
    const float* __restrict__ addm,          // [1032][1032]
    unsigned short* __restrict__ outp)       // [4128][1024] bf16
{
  __shared__ unsigned short Kc[64 * 72];  // [m][d], padded stride 72
  __shared__ unsigned short Vs[64 * 72];  // [d][m], padded stride 72
  __shared__ unsigned short Ps[64 * 72];  // [i][m], padded stride 72
  const int t = threadIdx.x;
  const int w = t >> 6, lane = t & 63, lr = lane & 15, lg = lane >> 4;
  const int bid = blockIdx.x;
  const int nb = (bid & 7) * 136 + (bid >> 3);
  const int bh = nb / 17, rt = nb - bh * 17;
  const int i_base = rt * 64 + w * 16;

  // hoist Kr A-fragments (rows i_base..i_base+15, d 0..63)
  bf16x8 akr[2];
  {
    int row = i_base + lr; if (row > NSEQ - 1) row = NSEQ - 1;
    const unsigned short* p = Kb + ((size_t)bh * NSEQ + row) * HD + lg * 8;
    akr[0] = *(const bf16x8*)(p);
    akr[1] = *(const bf16x8*)(p + 32);
  }

  f32x4 accP[4] = {};
  float lsum[4] = {0.f, 0.f, 0.f, 0.f};

  for (int mt = 0; mt < 17; ++mt) {
    const int mB = mt * 64;
    // stage Kc[m][d] and Vs[d][m]
    #pragma unroll
    for (int q = 0; q < 2; ++q) {
      const int o = t + (q << 8);          // 0..511, 64 rows x 8 chunks
      const int row = o >> 3, ch = o & 7;
      int mrow = mB + row; if (mrow > NSEQ - 1) mrow = NSEQ - 1;
      bf16x8 kv = *(const bf16x8*)(Kb + ((size_t)bh * NSEQ + mrow) * HD + ch * 8);
      *(bf16x8*)(Kc + row * 72 + ch * 8) = kv;
      int cb = mB + ch * 8; if (cb + 8 > NSEQ) cb = NSEQ - 8;
      bf16x8 vv = *(const bf16x8*)(Vt + ((size_t)bh * HD + row) * NSEQ + cb);
      *(bf16x8*)(Vs + row * 72 + ch * 8) = vv;
    }
    __syncthreads();

    // S = Kr @ Kc^T  (16 x 64 per wave)
    f32x4 s[4];
    #pragma unroll
    for (int fn = 0; fn < 4; ++fn) {
      f32x4 z = {0.f, 0.f, 0.f, 0.f};
      bf16x8 b0 = *(const bf16x8*)(Kc + (16 * fn + lr) * 72 + lg * 8);
      bf16x8 b1 = *(const bf16x8*)(Kc + (16 * fn + lr) * 72 + 32 + lg * 8);
      z = __builtin_amdgcn_mfma_f32_16x16x32_bf16(akr[0], b0, z, 0, 0, 0);
      z = __builtin_amdgcn_mfma_f32_16x16x32_bf16(akr[1], b1, z, 0, 0, 0);
      s[fn] = z;
    }

    // p = exp(scale*s + add); accumulate row sums; stash bf16 P in LDS
    const int irow_base = i_base + lg * 4;
    #pragma unroll
    for (int fn = 0; fn < 4; ++fn) {
      const int mcol = mB + 16 * fn + lr;
      const int mc = mcol > NSEQ - 1 ? NSEQ - 1 : mcol;
      #pragma unroll
      for (int r = 0; r < 4; ++r) {
        int irow = irow_base + r; int ic = irow > NSEQ - 1 ? NSEQ - 1 : irow;
        float sv = s[fn][r] * SCALE + addm[(size_t)ic * NSEQ + mc];
        float p = (mcol < NSEQ) ? __expf(sv) : 0.f;
        lsum[r] += p;
        Ps[(w * 16 + lg * 4 + r) * 72 + 16 * fn + lr] = f2bf(p);
      }
    }

    // PV: accP += P @ V
    bf16x8 pa0 = *(const bf16x8*)(Ps + (w * 16 + lr) * 72 + lg * 8);
    bf16x8 pa1 = *(const bf16x8*)(Ps + (w * 16 + lr) * 72 + 32 + lg * 8);
    #pragma unroll
    for (int fd = 0; fd < 4; ++fd) {
      bf16x8 v0 = *(const bf16x8*)(Vs + (16 * fd + lr) * 72 + lg * 8);
      bf16x8 v1 = *(const bf16x8*)(Vs + (16 * fd + lr) * 72 + 32 + lg * 8);
      accP[fd] = __builtin_amdgcn_mfma_f32_16x16x32_bf16(pa0, v0, accP[fd], 0, 0, 0);
      accP[fd] = __builtin_amdgcn_mfma_f32_16x16x32_bf16(pa1, v1, accP[fd], 0, 0, 0);
    }
    __syncthreads();
  }

  // reduce lsum across the 16 lanes of this row-group
  #pragma unroll
  for (int r = 0; r < 4; ++r) {
    float v = lsum[r];
    v += __shfl_xor(v, 1); v += __shfl_xor(v, 2);
    v += __shfl_xor(v, 4); v += __shfl_xor(v, 8);
    lsum[r] = v;
  }

  const int b = bh >> 4, hh = bh & 15;
  #pragma unroll
  for (int fd = 0; fd < 4; ++fd) {
    #pragma unroll
    for (int r = 0; r < 4; ++r) {
      const int irow = i_base + lg * 4 + r;
      if (irow < NSEQ) {
        const float val = 0.8f * accP[fd][r] / lsum[r];
        outp[(size_t)(b * NSEQ + irow) * CDIM + hh * 64 + 16 * fd + lr] = f2bf(val);
      }
    }
  }
}

// op += 1.2 * rcs @ V  (per head). Streaming-BW kernel.
// grid: 1088 blocks (17 i-tiles x 64 heads), XCD-swizzled.
__global__ __launch_bounds__(256, 6) void rcs_gemm(
    const float* __restrict__ rcs,           // [64][1032][1032] f32
    const unsigned short* __restrict__ Vt,   // [64][64][1032] bf16
    unsigned short* __restrict__ op)         // [4128][1024] bf16 (read-modify-write)
{
  __shared__ __align__(16) float As[64 * 64];            // [i][m] f32, XOR-swizzled chunks
  __shared__ __align__(16) unsigned short Bs2[64 * 64];  // [d][m] bf16, XOR-swizzled chunks
  const int t = threadIdx.x;
  const int w = t >> 6, lane = t & 63, lr = lane & 15, lg = lane >> 4;
  const int bid = blockIdx.x;
  const int nb = (bid & 7) * 136 + (bid >> 3);
  const int bh = nb / 17, it = nb - bh * 17;
  const int i_base = it * 64;
  const float* rbase = rcs + (size_t)bh * NSEQ * NSEQ;
  const unsigned short* vbase = Vt + (size_t)bh * HD * NSEQ;

  const int arow = w * 16 + lr;   // this lane's A-row (local)
  f32x4 acc[4] = {};

  for (int step = 0; step < 16; ++step) {
    const int mB = step * 64;
    // stage A tile [64 i][64 m] f32 (16KB): linear LDS dest, inverse-swizzled source
    #pragma unroll
    for (int q = 0; q < 4; ++q) {
      const int p = t + (q << 8);
      const int row = p >> 4, sch = p & 15;
      const int gch = (sch & 8) | ((sch ^ row) & 7);
      int grow = i_base + row; if (grow > NSEQ - 1) grow = NSEQ - 1;
      gl16(rbase + (size_t)grow * NSEQ + mB + gch * 4, (void*)(As + p * 4));
    }
    // stage B tile [64 d][64 m] bf16 (8KB)
    #pragma unroll
    for (int q = 0; q < 2; ++q) {
      const int p = t + (q << 8);
      const int row = p >> 3, sch = p & 7;
      const int gch = (sch ^ row) & 7;
      gl16(vbase + (size_t)row * NSEQ + mB + gch * 8, (void*)(Bs2 + p * 8));
    }
    __syncthreads();

    // A-frags: i=arow, k = kf*32 + lg*8 (f32 chunks -> bf16)
    bf16x8 af[2];
    #pragma unroll
    for (int kf = 0; kf < 2; ++kf) {
      const float* ab = As + arow * 64;
      const int c0 = kf * 8 + 2 * lg;       // even, bit3 = kf
      const int s0 = (c0 & 8) | ((c0 ^ arow) & 7);
      const int s1 = (c0 & 8) | (((c0 + 1) ^ arow) & 7);
      f32x4 lo = *(const f32x4*)(ab + s0 * 4);
      f32x4 hi = *(const f32x4*)(ab + s1 * 4);
      bf16x8 a;
      a[0] = (short)f2bf(lo[0]); a[1] = (short)f2bf(lo[1]);
      a[2] = (short)f2bf(lo[2]); a[3] = (short)f2bf(lo[3]);
      a[4] = (short)f2bf(hi[0]); a[5] = (short)f2bf(hi[1]);
      a[6] = (short)f2bf(hi[2]); a[7] = (short)f2bf(hi[3]);
      af[kf] = a;
    }
    // B-frags + MFMA
    #pragma unroll
    for (int fd = 0; fd < 4; ++fd) {
      const int vrow = 16 * fd + lr;
      #pragma unroll
      for (int kf = 0; kf < 2; ++kf) {
        const int c = kf * 4 + lg;  // 0..7
        bf16x8 bv = *(const bf16x8*)(Bs2 + vrow * 64 + (c ^ (vrow & 7)) * 8);
        acc[fd] = __builtin_amdgcn_mfma_f32_16x16x32_bf16(af[kf], bv, acc[fd], 0, 0, 0);
      }
    }
    __syncthreads();
  }

  // K-tail: m = 1024..1031 (8 cols), register path, lg==0 lanes hold the data
  {
    bf16x8 at;
    #pragma unroll
    for (int j = 0; j < 8; ++j) at[j] = 0;
    if (lg == 0) {
      int gi = i_base + arow; if (gi > NSEQ - 1) gi = NSEQ - 1;
      const float* rp = rbase + (size_t)gi * NSEQ + 1024;
      f32x4 lo = *(const f32x4*)(rp);
      f32x4 hi = *(const f32x4*)(rp + 4);
      at[0] = (short)f2bf(lo[0]); at[1] = (short)f2bf(lo[1]);
      at[2] = (short)f2bf(lo[2]); at[3] = (short)f2bf(lo[3]);
      at[4] = (short)f2bf(hi[0]); at[5] = (short)f2bf(hi[1]);
      at[6] = (short)f2bf(hi[2]); at[7] = (short)f2bf(hi[3]);
    }
    #pragma unroll
    for (int fd = 0; fd < 4; ++fd) {
      bf16x8 bt;
      #pragma unroll
      for (int j = 0; j < 8; ++j) bt[j] = 0;
      if (lg == 0)
        bt = *(const bf16x8*)(vbase + (size_t)(16 * fd + lr) * NSEQ + 1024);
      acc[fd] = __builtin_amdgcn_mfma_f32_16x16x32_bf16(at, bt, acc[fd], 0, 0, 0);
    }
  }

  const int b = bh >> 4, hh = bh & 15;
  #pragma unroll
  for (int fd = 0; fd < 4; ++fd) {
    #pragma unroll
    for (int r = 0; r < 4; ++r) {
      const int irow = i_base + w * 16 + lg * 4 + r;
      if (irow < NSEQ) {
        const size_t o = (size_t)(b * NSEQ + irow) * CDIM + hh * 64 + 16 * fd + lr;
        op[o] = f2bf(bf2f(op[o]) + 1.2f * acc[fd][r]);
      }
    }
  }
}

extern "C" void kernel_launch(void* const* d_in, const int* in_sizes, int n_in,
                              void* d_out, int out_size, void* d_ws, size_t ws_size,
                              hipStream_t stream) {
  (void)in_sizes; (void)n_in; (void)out_size; (void)ws_size;
  const float* x      = (const float*)d_in[0];
  const float* qkv_w  = (const float*)d_in[1];
  const float* qkv_b  = (const float*)d_in[2];
  const float* proj_w = (const float*)d_in[3];
  const float* proj_b = (const float*)d_in[4];
  const float* addm   = (const float*)d_in[5];
  const float* rcs    = (const float*)d_in[6];
  float* out = (float*)d_out;

  char* ws = (char*)d_ws;
  unsigned short* x_bf = (unsigned short*)ws; ws += (size_t)BROWS * CDIM * 2;
  unsigned short* wkv  = (unsigned short*)ws; ws += (size_t)2048 * CDIM * 2;
  unsigned short* wp   = (unsigned short*)ws; ws += (size_t)1024 * CDIM * 2;
  unsigned short* Kb   = (unsigned short*)ws; ws += (size_t)64 * NSEQ * HD * 2;
  unsigned short* Vt   = (unsigned short*)ws; ws += (size_t)64 * HD * NSEQ * 2;
  unsigned short* op   = (unsigned short*)ws; ws += (size_t)BROWS * CDIM * 2;

  const int n1 = BROWS * CDIM / 4, n2 = 2048 * CDIM / 4, n3 = 1024 * CDIM / 4;
  convert_f32_bf16<<<(n1 + 255) / 256, 256, 0, stream>>>(x, x_bf, n1);
  convert_f32_bf16<<<(n2 + 255) / 256, 256, 0, stream>>>(qkv_w + 1024 * 1024, wkv, n2);
  convert_f32_bf16<<<(n3 + 255) / 256, 256, 0, stream>>>(proj_w, wp, n3);

  // K/V projection (q is unused by the reference math — skipped)
  gemm_bt<0><<<dim3(16, 33), 256, 0, stream>>>(x_bf, wkv, qkv_b + 1024, Kb, Vt, nullptr, BROWS, CDIM);
  attn_sm<<<1088, 256, 0, stream>>>(Kb, Vt, addm, op);
  rcs_gemm<<<1088, 256, 0, stream>>>(rcs, Vt, op);
  gemm_bt<1><<<dim3(8, 33), 256, 0, stream>>>(op, wp, proj_b, nullptr, nullptr, out, BROWS, CDIM);
}